// Round 14
// baseline (12612.585 us; speedup 1.0000x reference)
//
#include <hip/hip_runtime.h>

#define B_   16
#define T_   1600
#define D_   512
#define U_   1024
#define G_   4096
#define NWG  512            // 256 per direction, 4 units per WG; 2 WGs/CU
#define TPB  256            // 4 waves, 4-way K split
#define SSTR 1544           // staging row stride (ushorts)
#define GSTR 20             // gates row stride (floats)
#define HSTOFF 8192         // LDS: h image [16 b][2048 B] swizzled
#define SMEM_BYTES 49408    // staging 16*1544*2 dominates (runtime: 8192+32768)
#define X16OFF (1 << 18)

typedef __attribute__((ext_vector_type(8))) __bf16 bf16x8;
typedef __attribute__((ext_vector_type(4))) float  f32x4;
typedef __attribute__((ext_vector_type(2))) float  f32x2;
typedef __attribute__((ext_vector_type(4))) unsigned int uint4v;
typedef __attribute__((ext_vector_type(8))) unsigned short us8v;
typedef unsigned long long u64;
typedef unsigned int u32;

__device__ __forceinline__ unsigned short f2bf(float f) {
  unsigned u = __builtin_bit_cast(unsigned, f);
  u += 0x7FFFu + ((u >> 16) & 1u);          // RNE
  return (unsigned short)(u >> 16);
}
__device__ __forceinline__ bf16x8 cvt8(const float4 a, const float4 b) {
  us8v r;
  r[0]=f2bf(a.x); r[1]=f2bf(a.y); r[2]=f2bf(a.z); r[3]=f2bf(a.w);
  r[4]=f2bf(b.x); r[5]=f2bf(b.y); r[6]=f2bf(b.z); r[7]=f2bf(b.w);
  return __builtin_bit_cast(bf16x8, r);
}
__device__ __forceinline__ float sigm(float x){ return 1.f / (1.f + __expf(-x)); }
__device__ __forceinline__ float tanh_(float x){ return 1.f - 2.f / (__expf(2.f*x) + 1.f); }

// one-time x fp32 -> bf16
extern "C" __global__ void __launch_bounds__(256)
xcvt_kernel(const float* __restrict__ xin, unsigned short* __restrict__ x16) {
  const size_t i = ((size_t)blockIdx.x*256 + threadIdx.x) * 8;
  float4 a = *(const float4*)(xin + i);
  float4 b = *(const float4*)(xin + i + 4);
  *(us8v*)(x16 + i) = __builtin_bit_cast(us8v, cvt8(a, b));
}

extern "C" __global__ void __launch_bounds__(TPB, 2)
bilstm_kernel(const float* __restrict__ x, const int* __restrict__ xlen,
              const float* __restrict__ kf, const float* __restrict__ rkf, const float* __restrict__ bf_,
              const float* __restrict__ kb, const float* __restrict__ rkb, const float* __restrict__ bb_,
              float* __restrict__ out, u32* __restrict__ hbuf32,
              const unsigned short* __restrict__ x16, int use16)
{
  extern __shared__ char smem[];

  const int tid  = threadIdx.x;
  const int wg   = blockIdx.x;
  const int dir  = wg >> 8;
  const int slot = wg & 255;
  const int u0   = slot << 2;         // 4 units per WG

  if (wg == 0 && tid < B_)
    out[(size_t)B_*T_*2*U_ + tid] = (float)xlen[tid];

  const float* Km = dir ? kb  : kf;
  const float* Rm = dir ? rkb : rkf;
  const float* Bv = dir ? bb_ : bf_;

  const int kq = tid >> 6, l = tid & 63;
  const int q8 = (l >> 4) << 3;       // frag k sub-offset
  const int col = l & 15;             // col = gate*4 + unit_local

  // ---- one-time: stage 16-col weight slice -> LDS, extract 12 frags ----
  bf16x8 wx[4], wh[8];
  {
    unsigned short* stag = (unsigned short*)smem;
    for (int i = tid; i < 1536*16; i += TPB) {
      int k = i >> 4, c = i & 15;
      int gc = (c >> 2)*1024 + u0 + (c & 3);
      float wv = (k < D_) ? Km[(size_t)k*G_ + gc] : Rm[(size_t)(k-D_)*G_ + gc];
      stag[c*SSTR + k] = f2bf(wv);
    }
    __syncthreads();
    const unsigned short* srow = stag + col*SSTR;
    #pragma unroll
    for (int i = 0; i < 4; ++i)  wx[i] = *(const bf16x8*)(srow + kq*128 + i*32 + q8);
    #pragma unroll
    for (int i = 0; i < 8; ++i)  wh[i] = *(const bf16x8*)(srow + 512 + kq*256 + i*32 + q8);
    __syncthreads();   // staging dead; reuse: gates @0, hst @HSTOFF
  }

  float* gates = (float*)smem;        // [4 kq][16 b][GSTR]
  char*  hst   = smem + HSTOFF;       // [16 b][2048 B] swizzled
  float* gp    = gates + kq*(16*GSTR);
  const int drow0 = (l >> 4) << 2;

  // epilogue state (lanes 0-31): b = tid>>1, units eu2, eu2+1
  const int eb = tid >> 1, eu2 = (tid & 1) << 1;
  float bias[8]; float cc0 = 0.f, cc1 = 0.f;
  if (tid < 32) {
    #pragma unroll
    for (int g = 0; g < 4; ++g) {
      bias[2*g]   = Bv[g*1024 + u0 + eu2];
      bias[2*g+1] = Bv[g*1024 + u0 + eu2 + 1];
    }
  }

  // per-lane x bases (row = l&15)
  const float* xbase = x + (size_t)(l & 15)*T_*D_ + kq*128 + q8;
  const unsigned short* x16b = x16 + (size_t)(l & 15)*T_*D_ + kq*128 + q8;

  // h A-frag LDS read base
  const char* hrow = hst + (l & 15)*2048;
  const int   swz  = ((l & 15) & 7) << 4;
  const int   kb2  = (kq*256 + q8) << 1;   // byte base of this wave's h K-span

  const unsigned off0 = (unsigned)tid * 16;

  // prologue: x-projection for t=0
  f32x4 acc = {0.f, 0.f, 0.f, 0.f};
  {
    const int tg0 = dir ? (T_ - 1) : 0;
    if (use16) {
      const unsigned short* xA = x16b + (size_t)tg0 * D_;
      #pragma unroll
      for (int i = 0; i < 4; ++i)
        acc = __builtin_amdgcn_mfma_f32_16x16x32_bf16(*(const bf16x8*)(xA + i*32), wx[i], acc, 0, 0, 0);
    } else {
      const float* xA = xbase + (size_t)tg0 * D_;
      #pragma unroll
      for (int i = 0; i < 4; ++i) {
        float4 lo = *(const float4*)(xA + i*32);
        float4 hi = *(const float4*)(xA + i*32 + 4);
        acc = __builtin_amdgcn_mfma_f32_16x16x32_bf16(cvt8(lo, hi), wx[i], acc, 0, 0, 0);
      }
    }
  }

  for (int t = 0; t < T_; ++t) {
    const int tg = dir ? (T_ - 1 - t) : t;

    if (t > 0) {
      // fused poll+load: retry until all 8B granules carry tag t (R10 verbatim)
      const u32* hb = hbuf32 + (size_t)((t & 1)*2 + dir) * 16384;
      const unsigned tagv = (unsigned)t << 16;
      uint4v hv[16];
      long long guard = 0;
      for (;;) {
        #pragma unroll
        for (int j = 0; j < 16; ++j)
          asm volatile("global_load_dwordx4 %0, %1, %2 sc0 sc1"
                       : "=v"(hv[j]) : "v"(off0 + (unsigned)(j*4096)), "s"(hb));
        asm volatile("s_waitcnt vmcnt(0)" ::: "memory");
        __builtin_amdgcn_sched_barrier(0);
        unsigned bad = 0;
        #pragma unroll
        for (int j = 0; j < 16; ++j)
          bad |= (hv[j][0] ^ tagv) | (hv[j][2] ^ tagv);
        if (!(bad & 0xFFFF0000u)) break;
        __builtin_amdgcn_s_sleep(1);
        if (++guard > (1LL << 22)) break;
      }
      // strip tags, stage payload to LDS (swizzled)
      #pragma unroll
      for (int j = 0; j < 16; ++j) {
        u32 lo = __builtin_amdgcn_perm(hv[j][1], hv[j][0], 0x05040100u);
        u32 hi = __builtin_amdgcn_perm(hv[j][3], hv[j][2], 0x05040100u);
        *(u64*)(hst + j*2048 + ((tid << 3) ^ ((j & 7) << 4))) = ((u64)hi << 32) | lo;
      }
      __syncthreads();   // S2: h image staged

      // recurrent MFMAs from LDS; 2 accumulators break the dep chain
      f32x4 acc2 = {0.f, 0.f, 0.f, 0.f};
      #pragma unroll
      for (int i = 0; i < 8; i += 2) {
        bf16x8 a0 = *(const bf16x8*)(hrow + ((kb2 + i*64)     ^ swz));
        bf16x8 a1 = *(const bf16x8*)(hrow + ((kb2 + (i+1)*64) ^ swz));
        acc  = __builtin_amdgcn_mfma_f32_16x16x32_bf16(a0, wh[i],   acc,  0, 0, 0);
        acc2 = __builtin_amdgcn_mfma_f32_16x16x32_bf16(a1, wh[i+1], acc2, 0, 0, 0);
      }
      acc[0]+=acc2[0]; acc[1]+=acc2[1]; acc[2]+=acc2[2]; acc[3]+=acc2[3];
    }

    #pragma unroll
    for (int j = 0; j < 4; ++j) gp[(drow0 + j)*GSTR + col] = acc[j];
    __syncthreads();   // S3: gates ready; h-image reads done

    // epilogue: lanes 0-31; 4-way kq reduce from LDS; tagged self-publishing store
    if (tid < 32) {
      float g4[8];
      #pragma unroll
      for (int g = 0; g < 4; ++g) {
        float s0 = 0.f, s1 = 0.f;
        #pragma unroll
        for (int q = 0; q < 4; ++q) {
          const float* gq = gates + q*(16*GSTR) + eb*GSTR + g*4 + eu2;
          s0 += gq[0]; s1 += gq[1];
        }
        g4[2*g] = s0 + bias[2*g]; g4[2*g+1] = s1 + bias[2*g+1];
      }
      cc0 = sigm(g4[2])*cc0 + sigm(g4[0])*tanh_(g4[4]);
      cc1 = sigm(g4[3])*cc1 + sigm(g4[1])*tanh_(g4[5]);
      float h0 = sigm(g4[6])*tanh_(cc0);
      float h1 = sigm(g4[7])*tanh_(cc1);
      const unsigned tagw = (unsigned)(t + 1) << 16;
      u32 w0 = (u32)f2bf(h0) | tagw;
      u32 w1 = (u32)f2bf(h1) | tagw;
      u32* hdst = hbuf32 + (size_t)(((t & 1) ^ 1)*2 + dir)*16384 + (eb << 10) + u0 + eu2;
      __hip_atomic_store((u64*)hdst, ((u64)w1 << 32) | w0, __ATOMIC_RELAXED, __HIP_MEMORY_SCOPE_AGENT);
      f32x2 ho; ho.x = h0; ho.y = h1;   // out store off the critical path, cached
      *(f32x2*)(out + ((size_t)eb*T_ + tg)*(2*U_) + (dir << 10) + u0 + eu2) = ho;
    }

    if (t + 1 < T_) {
      // x-projection for t+1 (overlaps h-store propagation)
      const int tg1 = dir ? (T_ - 2 - t) : (t + 1);
      f32x4 nacc = {0.f, 0.f, 0.f, 0.f};
      if (use16) {
        const unsigned short* xA = x16b + (size_t)tg1 * D_;
        #pragma unroll
        for (int i = 0; i < 4; ++i)
          nacc = __builtin_amdgcn_mfma_f32_16x16x32_bf16(*(const bf16x8*)(xA + i*32), wx[i], nacc, 0, 0, 0);
      } else {
        const float* xA = xbase + (size_t)tg1 * D_;
        #pragma unroll
        for (int i = 0; i < 4; ++i) {
          float4 lo = *(const float4*)(xA + i*32);
          float4 hi = *(const float4*)(xA + i*32 + 4);
          nacc = __builtin_amdgcn_mfma_f32_16x16x32_bf16(cvt8(lo, hi), wx[i], nacc, 0, 0, 0);
        }
      }
      acc = nacc;
    }
  }
}

extern "C" void kernel_launch(void* const* d_in, const int* in_sizes, int n_in,
                              void* d_out, int out_size, void* d_ws, size_t ws_size,
                              hipStream_t stream) {
  const float* x   = (const float*)d_in[0];
  const int*   xl  = (const int*)d_in[1];
  const float* kf  = (const float*)d_in[2];
  const float* rkf = (const float*)d_in[3];
  const float* bf_ = (const float*)d_in[4];
  const float* kb  = (const float*)d_in[5];
  const float* rkb = (const float*)d_in[6];
  const float* bb_ = (const float*)d_in[7];
  float* out = (float*)d_out;

  u32* hbuf32 = (u32*)d_ws;                                       // 4 x 64KB tagged h images
  unsigned short* x16 = (unsigned short*)((char*)d_ws + X16OFF);  // 26.2 MB bf16 x

  const size_t need = (size_t)X16OFF + (size_t)B_*T_*D_*2;
  const int use16 = (ws_size >= need) ? 1 : 0;

  (void)hipMemsetAsync(d_ws, 0, X16OFF, stream);    // zero all tags (graph-safe)
  if (use16)
    xcvt_kernel<<<6400, 256, 0, stream>>>(x, x16);

  bilstm_kernel<<<NWG, TPB, SMEM_BYTES, stream>>>(x, xl, kf, rkf, bf_, kb, rkb, bb_,
                                                  out, hbuf32, x16, use16);
}

// Round 15
// 5179.786 us; speedup vs baseline: 2.4350x; 2.4350x over previous
//
#include <hip/hip_runtime.h>

#define B_   16
#define T_   1600
#define D_   512
#define U_   1024
#define G_   4096           // 4*U
#define NWG  256            // 128 per direction, 1 per CU
#define TPB  256
#define KTOT 1536           // D + U
#define APAD 1544           // weight staging pad (ushort elems)
#define ROWB (APAD*2)
#define X16OFF (1 << 18)    // x16 image offset in d_ws; hbuf32 = 4 x 64KB fills [0, 256KB)

typedef __attribute__((ext_vector_type(8))) __bf16 bf16x8;
typedef __attribute__((ext_vector_type(4))) float  f32x4;
typedef __attribute__((ext_vector_type(2))) float  f32x2;
typedef __attribute__((ext_vector_type(4))) unsigned int uint4v;
typedef __attribute__((ext_vector_type(8))) unsigned short us8v;
typedef unsigned long long u64;
typedef unsigned int u32;

__device__ __forceinline__ unsigned short f2bf(float f) {
  unsigned u = __builtin_bit_cast(unsigned, f);
  u += 0x7FFFu + ((u >> 16) & 1u);          // RNE
  return (unsigned short)(u >> 16);
}
__device__ __forceinline__ bf16x8 cvt8(const float4 a, const float4 b) {
  us8v r;
  r[0]=f2bf(a.x); r[1]=f2bf(a.y); r[2]=f2bf(a.z); r[3]=f2bf(a.w);
  r[4]=f2bf(b.x); r[5]=f2bf(b.y); r[6]=f2bf(b.z); r[7]=f2bf(b.w);
  return __builtin_bit_cast(bf16x8, r);
}
__device__ __forceinline__ float sigm(float x){ return 1.f / (1.f + __expf(-x)); }
__device__ __forceinline__ float tanh_(float x){ return 1.f - 2.f / (__expf(2.f*x) + 1.f); }

// one-time x fp32 -> bf16
extern "C" __global__ void __launch_bounds__(256)
xcvt_kernel(const float* __restrict__ xin, unsigned short* __restrict__ x16) {
  const size_t i = ((size_t)blockIdx.x*256 + threadIdx.x) * 8;
  float4 a = *(const float4*)(xin + i);
  float4 b = *(const float4*)(xin + i + 4);
  *(us8v*)(x16 + i) = __builtin_bit_cast(us8v, cvt8(a, b));
}

extern "C" __global__ void __launch_bounds__(TPB, 1)
bilstm_kernel(const float* __restrict__ x, const int* __restrict__ xlen,
              const float* __restrict__ kf, const float* __restrict__ rkf, const float* __restrict__ bf_,
              const float* __restrict__ kb, const float* __restrict__ rkb, const float* __restrict__ bb_,
              float* __restrict__ out, u32* __restrict__ hbuf32,
              const unsigned short* __restrict__ x16, int use16)
{
  extern __shared__ char smem[];

  const int tid = threadIdx.x;
  const int wg  = blockIdx.x;
  const int dir = wg >> 7;
  const int slot = wg & 127;
  const int u0  = slot << 3;

  if (wg == 0 && tid < B_)
    out[(size_t)B_*T_*2*U_ + tid] = (float)xlen[tid];

  const float* Km = dir ? kb  : kf;
  const float* Rm = dir ? rkb : rkf;
  const float* Bv = dir ? bb_ : bf_;

  const int w = tid >> 6, l = tid & 63;
  const int ntile = w & 1, khalf = w >> 1;

  // ---- one-time: stage weight slice [1536][32] -> LDS bf16 ----
  {
    char* Wb = smem;
    for (int i = tid; i < KTOT*32; i += TPB) {
      int k = i >> 5, c = i & 31;
      int gc = ((c >> 3) << 10) + u0 + (c & 7);
      float wv = (k < D_) ? Km[(size_t)k*G_ + gc] : Rm[(size_t)(k-D_)*G_ + gc];
      *(unsigned short*)(Wb + c*ROWB + (k << 1)) = f2bf(wv);
    }
  }
  __syncthreads();

  // ---- one-time: pull 24 B-fragments into VGPRs ----
  bf16x8 wx[8], wh[16];
  {
    const char* Brow = smem + (ntile*16 + (l & 15))*ROWB + ((l >> 4) << 4);
    #pragma unroll
    for (int i = 0; i < 8; ++i)  wx[i] = *(const bf16x8*)(Brow + ((khalf*8 + i) << 6));
    #pragma unroll
    for (int i = 0; i < 16; ++i) wh[i] = *(const bf16x8*)(Brow + ((16 + khalf*16 + i) << 6));
  }
  __syncthreads();   // weight LDS dead; reuse: gates @0 (4KB), h-stage @4096 (32KB)

  float* gates = (float*)smem;            // [2 khalf][16 b][32 col]
  char*  hst   = smem + 4096;             // [16 b][2048 B] XOR-swizzled bf16 h
  float* gp    = gates + khalf*512;
  const int drow0 = (l >> 4) << 2, dcol = ntile*16 + (l & 15);

  // epilogue-lane state (wave 0): 2 units each
  const int eb = tid >> 2, eup = (tid & 3) << 1;
  float bi0=0, bi1=0, bff0=0, bff1=0, bz0=0, bz1=0, bo0=0, bo1=0, c0=0, c1=0;
  if (tid < 64) {
    bi0 = Bv[u0+eup];        bi1 = Bv[u0+eup+1];
    bff0= Bv[1024+u0+eup];   bff1= Bv[1024+u0+eup+1];
    bz0 = Bv[2048+u0+eup];   bz1 = Bv[2048+u0+eup+1];
    bo0 = Bv[3072+u0+eup];   bo1 = Bv[3072+u0+eup+1];
  }

  // per-lane x bases
  const float* xbase = x + (size_t)(l & 15)*T_*D_ + khalf*256 + ((l >> 4) << 3);
  const unsigned short* x16b = x16 + (size_t)(l & 15)*T_*D_ + khalf*256 + ((l >> 4) << 3);

  // A-frag LDS read base for h
  const char* hrow  = hst + (l & 15)*2048;
  const int   kbase = (khalf*512 + ((l >> 4) << 3)) << 1;
  const int   swz   = ((l & 15) & 7) << 4;

  const unsigned off0 = (unsigned)tid * 16;   // consumer poll byte offsets: off0 + j*4096

  // prologue: x-projection for t=0
  f32x4 acc = {0.f, 0.f, 0.f, 0.f};
  {
    const int tg0 = dir ? (T_ - 1) : 0;
    if (use16) {
      const unsigned short* xA = x16b + (size_t)tg0 * D_;
      #pragma unroll
      for (int i = 0; i < 8; ++i)
        acc = __builtin_amdgcn_mfma_f32_16x16x32_bf16(*(const bf16x8*)(xA + i*32), wx[i], acc, 0, 0, 0);
    } else {
      const float* xA = xbase + (size_t)tg0 * D_;
      #pragma unroll
      for (int i = 0; i < 8; ++i) {
        float4 lo = *(const float4*)(xA + i*32);
        float4 hi = *(const float4*)(xA + i*32 + 4);
        acc = __builtin_amdgcn_mfma_f32_16x16x32_bf16(cvt8(lo, hi), wx[i], acc, 0, 0, 0);
      }
    }
  }

  for (int t = 0; t < T_; ++t) {
    const int tg = dir ? (T_ - 1 - t) : t;

    if (t > 0) {
      // ---- fused poll+load: tagged h image, retry until all tags == t ----
      const u32* hb = hbuf32 + (size_t)((t & 1)*2 + dir) * 16384;
      const unsigned tagv = (unsigned)t << 16;
      uint4v hv[16];
      long long guard = 0;
      for (;;) {
        #pragma unroll
        for (int j = 0; j < 16; ++j)
          asm volatile("global_load_dwordx4 %0, %1, %2 sc0 sc1"
                       : "=v"(hv[j]) : "v"(off0 + (unsigned)(j*4096)), "s"(hb));
        asm volatile("s_waitcnt vmcnt(0)" ::: "memory");
        __builtin_amdgcn_sched_barrier(0);
        unsigned bad = 0;
        #pragma unroll
        for (int j = 0; j < 16; ++j)
          bad |= (hv[j][0] ^ tagv) | (hv[j][2] ^ tagv);   // one tag per 8B producer granule
        if (!(bad & 0xFFFF0000u)) break;
        __builtin_amdgcn_s_sleep(1);
        if (++guard > (1LL << 22)) break;
      }
      // strip tags, pack bf16 pairs, stage to LDS (swizzled)
      #pragma unroll
      for (int j = 0; j < 16; ++j) {
        u32 lo = __builtin_amdgcn_perm(hv[j][1], hv[j][0], 0x05040100u);
        u32 hi = __builtin_amdgcn_perm(hv[j][3], hv[j][2], 0x05040100u);
        u64 v = ((u64)hi << 32) | lo;
        *(u64*)(hst + j*2048 + ((tid << 3) ^ ((j & 7) << 4))) = v;
      }
      __syncthreads();   // S2: h image staged

      // recurrent MFMAs from LDS; 2 accumulators break the dep chain
      f32x4 acc2 = {0.f, 0.f, 0.f, 0.f};
      #pragma unroll
      for (int i = 0; i < 16; i += 2) {
        bf16x8 a0 = *(const bf16x8*)(hrow + ((kbase + i*64)     ^ swz));
        bf16x8 a1 = *(const bf16x8*)(hrow + ((kbase + (i+1)*64) ^ swz));
        acc  = __builtin_amdgcn_mfma_f32_16x16x32_bf16(a0, wh[i],   acc,  0, 0, 0);
        acc2 = __builtin_amdgcn_mfma_f32_16x16x32_bf16(a1, wh[i+1], acc2, 0, 0, 0);
      }
      acc[0]+=acc2[0]; acc[1]+=acc2[1]; acc[2]+=acc2[2]; acc[3]+=acc2[3];
    }

    #pragma unroll
    for (int j = 0; j < 4; ++j) gp[(drow0 + j)*32 + dcol] = acc[j];
    __syncthreads();   // S3: gates ready; h-image reads done

    // epilogue: wave 0. Tagged h store is self-publishing: no drain, no flag.
    if (tid < 64) {
      const float* g0 = gates + eb*32 + eup;
      float gi0 = g0[0]  + g0[512] + bi0,  gi1 = g0[1]  + g0[513] + bi1;
      float gf0 = g0[8]  + g0[520] + bff0, gf1 = g0[9]  + g0[521] + bff1;
      float gz0 = g0[16] + g0[528] + bz0,  gz1 = g0[17] + g0[529] + bz1;
      float go0 = g0[24] + g0[536] + bo0,  go1 = g0[25] + g0[537] + bo1;
      c0 = sigm(gf0)*c0 + sigm(gi0)*tanh_(gz0);
      c1 = sigm(gf1)*c1 + sigm(gi1)*tanh_(gz1);
      float h0 = sigm(go0)*tanh_(c0);
      float h1 = sigm(go1)*tanh_(c1);
      const unsigned tagw = (unsigned)(t + 1) << 16;
      u32 w0 = (u32)f2bf(h0) | tagw;
      u32 w1 = (u32)f2bf(h1) | tagw;
      u32* hdst = hbuf32 + (size_t)(((t & 1) ^ 1)*2 + dir)*16384 + (eb << 10) + u0 + eup;
      __hip_atomic_store((u64*)hdst, ((u64)w1 << 32) | w0, __ATOMIC_RELAXED, __HIP_MEMORY_SCOPE_AGENT);
      f32x2 ho; ho.x = h0; ho.y = h1;   // out store off the critical path, cached
      *(f32x2*)(out + ((size_t)eb*T_ + tg)*(2*U_) + (dir << 10) + u0 + eup) = ho;
    }

    if (t + 1 < T_) {
      // x-projection for t+1 (overlaps h-store propagation)
      const int tg1 = dir ? (T_ - 2 - t) : (t + 1);
      f32x4 nacc = {0.f, 0.f, 0.f, 0.f};
      if (use16) {
        const unsigned short* xA = x16b + (size_t)tg1 * D_;
        #pragma unroll
        for (int i = 0; i < 8; ++i)
          nacc = __builtin_amdgcn_mfma_f32_16x16x32_bf16(*(const bf16x8*)(xA + i*32), wx[i], nacc, 0, 0, 0);
      } else {
        const float* xA = xbase + (size_t)tg1 * D_;
        #pragma unroll
        for (int i = 0; i < 8; ++i) {
          float4 lo = *(const float4*)(xA + i*32);
          float4 hi = *(const float4*)(xA + i*32 + 4);
          nacc = __builtin_amdgcn_mfma_f32_16x16x32_bf16(cvt8(lo, hi), wx[i], nacc, 0, 0, 0);
        }
      }
      acc = nacc;
    }
  }
}

extern "C" void kernel_launch(void* const* d_in, const int* in_sizes, int n_in,
                              void* d_out, int out_size, void* d_ws, size_t ws_size,
                              hipStream_t stream) {
  const float* x   = (const float*)d_in[0];
  const int*   xl  = (const int*)d_in[1];
  const float* kf  = (const float*)d_in[2];
  const float* rkf = (const float*)d_in[3];
  const float* bf_ = (const float*)d_in[4];
  const float* kb  = (const float*)d_in[5];
  const float* rkb = (const float*)d_in[6];
  const float* bb_ = (const float*)d_in[7];
  float* out = (float*)d_out;

  u32* hbuf32 = (u32*)d_ws;                                       // 4 x 64KB tagged h images
  unsigned short* x16 = (unsigned short*)((char*)d_ws + X16OFF);  // 26.2 MB bf16 x

  const size_t need = (size_t)X16OFF + (size_t)B_*T_*D_*2;
  const int use16 = (ws_size >= need) ? 1 : 0;

  (void)hipMemsetAsync(d_ws, 0, X16OFF, stream);    // zero all tags (graph-safe)
  if (use16)
    xcvt_kernel<<<6400, 256, 0, stream>>>(x, x16);

  const size_t smem = 32*(size_t)ROWB;   // 98,816 B (weight staging); runtime uses 36,864 B
  bilstm_kernel<<<NWG, TPB, smem, stream>>>(x, xl, kf, rkf, bf_, kb, rkb, bb_,
                                            out, hbuf32, x16, use16);
}